// Round 4
// baseline (110.867 us; speedup 1.0000x reference)
//
#include <hip/hip_runtime.h>

// Problem constants
#define N_FILTERS 1024
#define B_TOTAL   1024
#define IMG       64            // H = W = 64
#define PAD_DIM   70            // 64 + 2*3 padded image side
// Xt layout in d_ws: fp16 [PAD_DIM*PAD_DIM pixels][1024 batches]  (10 MB, LLC-resident)
// Window consumed per filter: padded rows i..i+9, cols j..j+9 (pool floor mode
// discards conv row/col 6, so only a 10x10 slab of the 11x11 window is read).

typedef _Float16 half2_t __attribute__((ext_vector_type(2)));

// ---------------- prep 1: zero the padded border of Xt ----------------
__global__ void zero_border_kernel(_Float16* __restrict__ Xt) {
    int pp = blockIdx.x;                 // padded pixel 0..4899
    int r = pp / PAD_DIM, c = pp - r * PAD_DIM;
    if (r >= 3 && r < 67 && c >= 3 && c < 67) return;   // interior written by transpose
    unsigned int* q = (unsigned int*)Xt + (size_t)pp * 512;   // 1024 fp16 = 512 dwords
    q[threadIdx.x] = 0u;
    q[threadIdx.x + 256] = 0u;
}

// ---------------- prep 2: transpose X [1024 b][4096 p] -> Xt fp16 [pixel][b] ----------------
__global__ __launch_bounds__(256) void transpose_kernel(
    const float* __restrict__ X, _Float16* __restrict__ Xt)
{
    __shared__ float T[64 * 65];         // [b_local][p_local], stride 65 kills conflicts
    const int pt = blockIdx.x & 63;      // pixel tile (64 pixels)
    const int bt = blockIdx.x >> 6;      // batch tile (64 batches)
    const int tx = threadIdx.x & 63, ty = threadIdx.x >> 6;

    #pragma unroll
    for (int pass = 0; pass < 16; ++pass) {
        int bl = pass * 4 + ty;          // lanes: consecutive pixels -> coalesced read
        T[bl * 65 + tx] = X[(size_t)(bt * 64 + bl) * 4096 + pt * 64 + tx];
    }
    __syncthreads();
    #pragma unroll
    for (int pass = 0; pass < 16; ++pass) {
        int pl = pass * 4 + ty;
        int p  = pt * 64 + pl;
        int r  = p >> 6, c = p & 63;
        // lanes: consecutive batches -> contiguous 128 B fp16 write
        Xt[(size_t)((r + 3) * PAD_DIM + (c + 3)) * 1024 + bt * 64 + tx]
            = (_Float16)T[tx * 65 + pl];
    }
}

// ---------------- main: lanes = batch, wave = one filter ----------------
// Block = 4 waves -> filters fg*4..fg*4+3, batches bg*128..bg*128+127 (2/lane via half2).
// All filter metadata (pos, weights, bias) is wave-uniform -> SGPRs via readfirstlane.
__global__ void filters_main(
    const half2_t* __restrict__ Xt2,   // [4900 pixels][512 half2]
    const float*   __restrict__ W,     // [F][25]
    const float*   __restrict__ bias,  // [F]
    const int*     __restrict__ pos,   // [F][2]
    float4*        __restrict__ out4)  // [B][1024 float4]  (= [B][F*4] floats)
{
    const int t    = threadIdx.x;
    const int lane = t & 63;
    const int w    = t >> 6;                       // wave id 0..3
    const int bg   = blockIdx.x & 7;               // batch group (128 batches)
    const int fg   = blockIdx.x >> 3;              // filter group (4 filters)

    const int f  = fg * 4 + w;
    const int sf = __builtin_amdgcn_readfirstlane(f);
    const int si = __builtin_amdgcn_readfirstlane(pos[2 * sf]);       // row i, 0..59
    const int sj = __builtin_amdgcn_readfirstlane(pos[2 * sf + 1]);   // col j, 0..59

    float wk[25];
    const float* wp = W + sf * 25;                 // scalar address -> s_load
    #pragma unroll
    for (int k = 0; k < 25; ++k) wk[k] = wp[k];

    const int pb = bg * 64 + lane;                 // half2 index within 512 per pixel

    float accA[36], accB[36];
    #pragma unroll
    for (int k = 0; k < 36; ++k) { accA[k] = 0.0f; accB[k] = 0.0f; }

    #pragma unroll
    for (int wr = 0; wr < 10; ++wr) {
        const half2_t* rowp = Xt2 + (size_t)((si + wr) * PAD_DIM + sj) * 512 + pb;
        float inA[10], inB[10];
        #pragma unroll
        for (int wc = 0; wc < 10; ++wc) {
            // pixel stride in Xt2 is 512 half2 (one padded-image column step)
            half2_t h = rowp[(size_t)wc * 512];    // 1 dword, lanes coalesced 256 B
            inA[wc] = (float)h.x;
            inB[wc] = (float)h.y;
        }
        // conv row y uses window rows y..y+4  =>  y in [max(0,wr-4), min(5,wr)]
        #pragma unroll
        for (int y = 0; y < 6; ++y) {
            if (y >= ((wr > 4) ? (wr - 4) : 0) && y <= ((wr < 5) ? wr : 5)) {
                const int r = wr - y;
                #pragma unroll
                for (int x = 0; x < 6; ++x) {
                    #pragma unroll
                    for (int c = 0; c < 5; ++c) {
                        accA[y * 6 + x] = fmaf(wk[r * 5 + c], inA[x + c], accA[y * 6 + x]);
                        accB[y * 6 + x] = fmaf(wk[r * 5 + c], inB[x + c], accB[y * 6 + x]);
                    }
                }
            }
        }
    }

    // 3x3 maxpool (stride 3) over the 6x6 conv grid -> 2x2; bias after max
    const float bv = bias[sf];
    float4 oA, oB;
    {
        float mA[4], mB[4];
        #pragma unroll
        for (int py = 0; py < 2; ++py) {
            #pragma unroll
            for (int px = 0; px < 2; ++px) {
                float a = accA[(3 * py) * 6 + 3 * px];
                float b = accB[(3 * py) * 6 + 3 * px];
                #pragma unroll
                for (int dy = 0; dy < 3; ++dy)
                    #pragma unroll
                    for (int dx = 0; dx < 3; ++dx) {
                        a = fmaxf(a, accA[(3 * py + dy) * 6 + (3 * px + dx)]);
                        b = fmaxf(b, accB[(3 * py + dy) * 6 + (3 * px + dx)]);
                    }
                mA[py * 2 + px] = a + bv;
                mB[py * 2 + px] = b + bv;
            }
        }
        oA.x = mA[0]; oA.y = mA[1]; oA.z = mA[2]; oA.w = mA[3];
        oB.x = mB[0]; oB.y = mB[1]; oB.z = mB[2]; oB.w = mB[3];
    }

    // out[b][f*4 .. f*4+3] as one float4; waves 0..3 of this block fill the same
    // 64 B region (cols fg*16..fg*16+15) for each b -> merges in L2.
    const int b = bg * 128 + lane * 2;
    out4[(size_t)b * 1024 + f]       = oA;
    out4[(size_t)(b + 1) * 1024 + f] = oB;
}

extern "C" void kernel_launch(void* const* d_in, const int* in_sizes, int n_in,
                              void* d_out, int out_size, void* d_ws, size_t ws_size,
                              hipStream_t stream) {
    const float* X    = (const float*)d_in[0];
    const float* W    = (const float*)d_in[1];
    const float* bias = (const float*)d_in[2];
    const int*   pos  = (const int*)d_in[3];
    float4* out4 = (float4*)d_out;
    _Float16* Xt = (_Float16*)d_ws;        // 70*70*1024 fp16 = 10 MB

    zero_border_kernel<<<PAD_DIM * PAD_DIM, 256, 0, stream>>>(Xt);
    transpose_kernel<<<1024, 256, 0, stream>>>(X, Xt);
    filters_main<<<2048, 256, 0, stream>>>((const half2_t*)Xt, W, bias, pos, out4);
}

// Round 5
// 99.554 us; speedup vs baseline: 1.1136x; 1.1136x over previous
//
#include <hip/hip_runtime.h>

// Problem constants
#define N_FILTERS 1024
#define B_TOTAL   1024
#define IMG       64            // H = W = 64
#define PAD_DIM   70            // 64 + 2*3 padded image side
// Xt layout in d_ws: fp16 [PAD_DIM*PAD_DIM pixels][1024 batches]  (10 MB).
// Per-XCD hot slice (bg pinned via blockIdx&7): 4900 px * 256 B = 1.25 MB -> fits 4 MB L2.
// Window consumed per filter: padded rows i..i+9, cols j..j+9 (pool floor mode
// discards conv row/col 6, so only a 10x10 slab of the 11x11 window is read).

typedef _Float16 half2_t __attribute__((ext_vector_type(2)));
typedef float    fvec2  __attribute__((ext_vector_type(2)));

// ---------------- prep 1: zero the padded border of Xt ----------------
__global__ void zero_border_kernel(_Float16* __restrict__ Xt) {
    int pp = blockIdx.x;                 // padded pixel 0..4899
    int r = pp / PAD_DIM, c = pp - r * PAD_DIM;
    if (r >= 3 && r < 67 && c >= 3 && c < 67) return;   // interior written by transpose
    unsigned int* q = (unsigned int*)Xt + (size_t)pp * 512;   // 1024 fp16 = 512 dwords
    q[threadIdx.x] = 0u;
    q[threadIdx.x + 256] = 0u;
}

// ---------------- prep 2: transpose X [1024 b][4096 p] -> Xt fp16 [pixel][b] ----------------
__global__ __launch_bounds__(256) void transpose_kernel(
    const float* __restrict__ X, _Float16* __restrict__ Xt)
{
    __shared__ float T[64 * 65];         // [b_local][p_local], stride 65 kills conflicts
    const int pt = blockIdx.x & 63;      // pixel tile (64 pixels)
    const int bt = blockIdx.x >> 6;      // batch tile (64 batches)
    const int tx = threadIdx.x & 63, ty = threadIdx.x >> 6;

    #pragma unroll
    for (int pass = 0; pass < 16; ++pass) {
        int bl = pass * 4 + ty;          // lanes: consecutive pixels -> coalesced read
        T[bl * 65 + tx] = X[(size_t)(bt * 64 + bl) * 4096 + pt * 64 + tx];
    }
    __syncthreads();
    #pragma unroll
    for (int pass = 0; pass < 16; ++pass) {
        int pl = pass * 4 + ty;
        int p  = pt * 64 + pl;
        int r  = p >> 6, c = p & 63;
        // lanes: consecutive batches -> contiguous 128 B fp16 write
        Xt[(size_t)((r + 3) * PAD_DIM + (c + 3)) * 1024 + bt * 64 + tx]
            = (_Float16)T[tx * 65 + pl];
    }
}

// ---------------- main: lanes = batch, wave = one filter, packed-f32 math ----------------
// Block = 4 waves -> filters fg*4..fg*4+3, batches bg*128..bg*128+127 (2/lane via half2).
// Accumulators are float2 (batch pair) -> v_pk_fma_f32 halves conv VALU cycles.
__global__ __launch_bounds__(256, 3) void filters_main(
    const half2_t* __restrict__ Xt2,   // [4900 pixels][512 half2]
    const float*   __restrict__ W,     // [F][25]
    const float*   __restrict__ bias,  // [F]
    const int*     __restrict__ pos,   // [F][2]
    float4*        __restrict__ out4)  // [B][1024 float4]  (= [B][F*4] floats)
{
    const int t    = threadIdx.x;
    const int lane = t & 63;
    const int w    = t >> 6;                       // wave id 0..3
    const int bg   = blockIdx.x & 7;               // batch group (128 batches) -> XCD pin
    const int fg   = blockIdx.x >> 3;              // filter group (4 filters)

    const int f  = fg * 4 + w;
    const int sf = __builtin_amdgcn_readfirstlane(f);
    const int si = __builtin_amdgcn_readfirstlane(pos[2 * sf]);       // row i, 0..59
    const int sj = __builtin_amdgcn_readfirstlane(pos[2 * sf + 1]);   // col j, 0..59

    float wk[25];
    const float* wp = W + sf * 25;                 // scalar address -> s_load into SGPRs
    #pragma unroll
    for (int k = 0; k < 25; ++k) wk[k] = wp[k];

    const int pb = bg * 64 + lane;                 // half2 index within 512 per pixel

    fvec2 acc[36];
    #pragma unroll
    for (int k = 0; k < 36; ++k) acc[k] = (fvec2)0.0f;

    #pragma unroll
    for (int wr = 0; wr < 10; ++wr) {
        const half2_t* rowp = Xt2 + (size_t)((si + wr) * PAD_DIM + sj) * 512 + pb;
        fvec2 in2[10];
        #pragma unroll
        for (int wc = 0; wc < 10; ++wc) {
            // pixel stride in Xt2 is 512 half2 (one padded-image column step)
            half2_t h = rowp[(size_t)wc * 512];    // 1 dword, lanes coalesced 256 B
            in2[wc].x = (float)h.x;
            in2[wc].y = (float)h.y;
        }
        // conv row y uses window rows y..y+4  =>  y in [max(0,wr-4), min(5,wr)]
        #pragma unroll
        for (int y = 0; y < 6; ++y) {
            if (y >= ((wr > 4) ? (wr - 4) : 0) && y <= ((wr < 5) ? wr : 5)) {
                const int r = wr - y;
                #pragma unroll
                for (int x = 0; x < 6; ++x) {
                    #pragma unroll
                    for (int c = 0; c < 5; ++c)
                        acc[y * 6 + x] = wk[r * 5 + c] * in2[x + c] + acc[y * 6 + x];
                }
            }
        }
    }

    // 3x3 maxpool (stride 3) over the 6x6 conv grid -> 2x2; bias after max
    const float bv = bias[sf];
    float4 oA, oB;
    {
        float mA[4], mB[4];
        #pragma unroll
        for (int py = 0; py < 2; ++py) {
            #pragma unroll
            for (int px = 0; px < 2; ++px) {
                fvec2 m = acc[(3 * py) * 6 + 3 * px];
                #pragma unroll
                for (int dy = 0; dy < 3; ++dy)
                    #pragma unroll
                    for (int dx = 0; dx < 3; ++dx) {
                        fvec2 v = acc[(3 * py + dy) * 6 + (3 * px + dx)];
                        m.x = fmaxf(m.x, v.x);
                        m.y = fmaxf(m.y, v.y);
                    }
                mA[py * 2 + px] = m.x + bv;
                mB[py * 2 + px] = m.y + bv;
            }
        }
        oA.x = mA[0]; oA.y = mA[1]; oA.z = mA[2]; oA.w = mA[3];
        oB.x = mB[0]; oB.y = mB[1]; oB.z = mB[2]; oB.w = mB[3];
    }

    // out[b][f*4 .. f*4+3] as one float4; waves 0..3 of this block fill the same
    // 64 B line (cols fg*16..fg*16+15) for each b -> merges in L2.
    const int b = bg * 128 + lane * 2;
    out4[(size_t)b * 1024 + f]       = oA;
    out4[(size_t)(b + 1) * 1024 + f] = oB;
}

extern "C" void kernel_launch(void* const* d_in, const int* in_sizes, int n_in,
                              void* d_out, int out_size, void* d_ws, size_t ws_size,
                              hipStream_t stream) {
    const float* X    = (const float*)d_in[0];
    const float* W    = (const float*)d_in[1];
    const float* bias = (const float*)d_in[2];
    const int*   pos  = (const int*)d_in[3];
    float4* out4 = (float4*)d_out;
    _Float16* Xt = (_Float16*)d_ws;        // 70*70*1024 fp16 = 10 MB

    zero_border_kernel<<<PAD_DIM * PAD_DIM, 256, 0, stream>>>(Xt);
    transpose_kernel<<<1024, 256, 0, stream>>>(X, Xt);
    filters_main<<<2048, 256, 0, stream>>>((const half2_t*)Xt, W, bias, pos, out4);
}